// Round 8
// baseline (1067.312 us; speedup 1.0000x reference)
//
#include <hip/hip_runtime.h>
#include <hip/hip_cooperative_groups.h>

namespace cg = cooperative_groups;

#define N_NODES 10000
#define N_EDGES 320000
#define MPAD 10112   // 158 * 64
#define NBIN 10048
#define CHUNK 2048
#define NCH 157      // ceil(E / CHUNK)
#define PREP_TOT 1525760L

typedef unsigned short u16;
typedef short bf16x8 __attribute__((ext_vector_type(8)));
typedef float f32x4 __attribute__((ext_vector_type(4)));

__device__ __forceinline__ u16 f2b(float f) {
  unsigned u = __builtin_bit_cast(unsigned, f);
  unsigned r = u + 0x7fffu + ((u >> 16) & 1u);
  return (u16)(r >> 16);
}
__device__ __forceinline__ unsigned pack2(float a, float b) {
  return (unsigned)f2b(a) | ((unsigned)f2b(b) << 16);
}
__device__ __forceinline__ float blo(unsigned u) { return __builtin_bit_cast(float, u << 16); }
__device__ __forceinline__ float bhi(unsigned u) { return __builtin_bit_cast(float, u & 0xffff0000u); }

// ---------------------------------------------------------- param structs ---
struct PP {
  const float *x; const int *ei;
  const float *w0, *w1, *w2, *fcw0, *injw0, *fcw1, *injw1, *outw;
  const float *fcb0, *injb0, *fcb1, *injb1, *alpha;
  u16 *xb, *w0t, *w1t, *w2t, *wc1t, *wc2t, *owt;
  float *bias1, *bias2;
  int *histR, *histC, *chunkoff, *cntR, *row_ptr, *csr;
  float *deg_inv;
};
struct CP {
  const u16 *xb, *w0t, *w1t, *w2t, *wc1t, *wc2t, *owt;
  const float *mp_b0, *mp_b1, *mp_b2, *bias1, *bias2, *out_b, *deg_inv;
  const int *row_ptr, *csr;
  u16 *tmp, *h, *cat1, *cat2, *C2;
  float *out;
};

// ----------------------------------------------------------- prep item ------
__device__ void prep_item(long i, const PP& P, float alpha) {
  if (i < 640000L) {  // x -> bf16, 4 floats per item
    float4 v = ((const float4*)P.x)[i];
    uint2 o;
    o.x = pack2(v.x, v.y);
    o.y = pack2(v.z, v.w);
    *(uint2*)(P.xb + 4 * i) = o;
    return;
  }
  i -= 640000L;
  if (i < 65536) { P.w0t[i] = f2b(P.w0[(i & 255) * 256 + (i >> 8)]); return; }
  i -= 65536;
  if (i < 65536) { P.w1t[i] = f2b(P.w1[(i & 255) * 256 + (i >> 8)]); return; }
  i -= 65536;
  if (i < 65536) { P.w2t[i] = f2b(P.w2[(i & 255) * 256 + (i >> 8)]); return; }
  i -= 65536;
  if (i < 262144) {  // Wcat1^T [512 n][512 k]
    int n = (int)(i >> 9), k = (int)(i & 511);
    float v = (k < 256) ? alpha * P.fcw0[k * 512 + n] : P.injw0[(k - 256) * 512 + n];
    P.wc1t[i] = f2b(v); return;
  }
  i -= 262144;
  if (i < 393216) {  // Wcat2^T [512 n][768 k]
    int n = (int)(i / 768), k = (int)(i % 768);
    float v = (k < 512) ? alpha * P.fcw1[k * 512 + n] : P.injw1[(k - 512) * 512 + n];
    P.wc2t[i] = f2b(v); return;
  }
  i -= 393216;
  if (i < 32768) {   // out_w^T [64 n][512 k]
    int n = (int)(i >> 9), k = (int)(i & 511);
    P.owt[i] = f2b(P.outw[k * 64 + n]); return;
  }
  i -= 32768;
  if (i < 512) { P.bias1[i] = alpha * P.fcb0[i] + P.injb0[i]; return; }
  i -= 512;
  if (i < 512) { P.bias2[i] = alpha * P.fcb1[i] + P.injb1[i]; return; }
}

// --------------------------------------------------------------- prolog -----
// ONE cooperative kernel: prep + hist -> col_scan -> row_scan -> place.
// Deterministic counting-sort CSR (replay-safe, no global RMW).
__global__ __launch_bounds__(256) void prolog(PP P) {
  __shared__ int sh[2 * NBIN];   // 80 KB: hist hr+hc / place cursor / scan tmp
  cg::grid_group grid = cg::this_grid();
  const int tid = threadIdx.x, bid = blockIdx.x, nb = gridDim.x;

  // P0a: prep (grid-stride)
  const float alpha = P.alpha[0];
  for (long i = (long)bid * 256 + tid; i < PREP_TOT; i += (long)nb * 256)
    prep_item(i, P, alpha);

  // P0b: per-chunk histograms (independent of prep)
  for (int ch = bid; ch < NCH; ch += nb) {
    for (int i = tid; i < 2 * NBIN; i += 256) sh[i] = 0;
    __syncthreads();
    const int e0 = ch * CHUNK;
    for (int j = tid; j < CHUNK; j += 256) {
      int e = e0 + j;
      if (e < N_EDGES) {
        atomicAdd(&sh[P.ei[e]], 1);
        atomicAdd(&sh[NBIN + P.ei[N_EDGES + e]], 1);
      }
    }
    __syncthreads();
    for (int i = tid; i < NBIN; i += 256) {
      P.histR[(size_t)ch * NBIN + i] = sh[i];
      P.histC[(size_t)ch * NBIN + i] = sh[NBIN + i];
    }
    __syncthreads();
  }
  grid.sync();

  // P1: per-bin scan across chunks -> chunkoff, cntR, deg_inv
  for (int r = bid * 256 + tid; r < MPAD; r += nb * 256) {
    if (r >= NBIN) { P.deg_inv[r] = 1.0f; continue; }
    int run = 0, dg = 0;
    for (int ch = 0; ch < NCH; ++ch) {
      P.chunkoff[(size_t)ch * NBIN + r] = run;
      run += P.histR[(size_t)ch * NBIN + r];
      dg  += P.histC[(size_t)ch * NBIN + r];
    }
    P.cntR[r] = run;
    P.deg_inv[r] = 1.0f / (float)(dg > 1 ? dg : 1);
  }
  grid.sync();

  // P2: exclusive scan over cntR -> row_ptr (block 0, 256 thr x 40 items)
  if (bid == 0) {
    int v[40];
    int s = 0;
#pragma unroll
    for (int i = 0; i < 40; ++i) {
      int id = tid * 40 + i;
      v[i] = (id < NBIN) ? P.cntR[id] : 0;
      s += v[i];
    }
    int lane = tid & 63, wid = tid >> 6;
    int incl = s;
#pragma unroll
    for (int off = 1; off < 64; off <<= 1) {
      int y = __shfl_up(incl, off, 64);
      if (lane >= off) incl += y;
    }
    if (lane == 63) sh[wid] = incl;
    __syncthreads();
    if (tid == 0) {
      int run = 0;
#pragma unroll
      for (int i = 0; i < 4; ++i) { sh[4 + i] = run; run += sh[i]; }
    }
    __syncthreads();
    int run = sh[4 + wid] + incl - s;
#pragma unroll
    for (int i = 0; i < 40; ++i) {
      int id = tid * 40 + i;
      if (id <= N_NODES) P.row_ptr[id] = run;
      run += v[i];
    }
  }
  grid.sync();

  // P3: placement (LDS cursor seeded from chunkoff; global state untouched)
  for (int ch = bid; ch < NCH; ch += nb) {
    for (int i = tid; i < NBIN; i += 256) sh[i] = P.chunkoff[(size_t)ch * NBIN + i];
    __syncthreads();
    const int e0 = ch * CHUNK;
    for (int j = tid; j < CHUNK; j += 256) {
      int e = e0 + j;
      if (e < N_EDGES) {
        int r = P.ei[e];
        int c = P.ei[N_EDGES + e];
        int rank = atomicAdd(&sh[r], 1);
        P.csr[P.row_ptr[r] + rank] = c;
      }
    }
    __syncthreads();
  }
}

// ----------------------------------------------------------- gemm phase -----
// 64x64 tile, 2-wave block (128 thr), wave = 32x64 strip (2x4 MFMA frags).
// Identical math to R7's gemm64; grid-stride over tiles.
template<int K, bool RELU, bool SCALE, bool F32OUT>
__device__ void gemm_phase(int nTm, int nTn,
                           const u16* __restrict__ A, int lda,
                           const u16* __restrict__ Bt,
                           const float* __restrict__ bias,
                           const float* __restrict__ scale,
                           u16* __restrict__ Cb, float* __restrict__ Cf, int ldc,
                           u16* As, u16* Bs, int bid, int nb, int tid) {
  const int wave = tid >> 6;
  const int lane = tid & 63;
  const int wr = wave * 32;
  const int lm = lane & 15;
  const int koff = (lane >> 4) * 8;
  const int srow = tid >> 2;
  const int scol = (tid & 3) * 16;
  const int q4 = (lane >> 4) * 4;
  const int nT = nTm * nTn;

  for (int t = bid; t < nT; t += nb) {
    const int m0 = (t % nTm) * 64;
    const int n0 = (t / nTm) * 64;
    const u16* Ag0 = A + (size_t)(m0 + srow) * lda + scol;
    const u16* Ag1 = A + (size_t)(m0 + srow + 32) * lda + scol;
    const u16* Bg0 = Bt + (size_t)(n0 + srow) * K + scol;
    const u16* Bg1 = Bt + (size_t)(n0 + srow + 32) * K + scol;
    u16* Asw0 = &As[srow * 72 + scol];
    u16* Asw1 = &As[(srow + 32) * 72 + scol];
    u16* Bsw0 = &Bs[srow * 72 + scol];
    u16* Bsw1 = &Bs[(srow + 32) * 72 + scol];

    f32x4 acc[2][4] = {};

    int4 pa0 = *(const int4*)(Ag0), pa1 = *(const int4*)(Ag0 + 8);
    int4 pa2 = *(const int4*)(Ag1), pa3 = *(const int4*)(Ag1 + 8);
    int4 pb0 = *(const int4*)(Bg0), pb1 = *(const int4*)(Bg0 + 8);
    int4 pb2 = *(const int4*)(Bg1), pb3 = *(const int4*)(Bg1 + 8);

#pragma unroll
    for (int kb = 0; kb < K; kb += 64) {
      __syncthreads();
      *(int4*)Asw0 = pa0; *(int4*)(Asw0 + 8) = pa1;
      *(int4*)Asw1 = pa2; *(int4*)(Asw1 + 8) = pa3;
      *(int4*)Bsw0 = pb0; *(int4*)(Bsw0 + 8) = pb1;
      *(int4*)Bsw1 = pb2; *(int4*)(Bsw1 + 8) = pb3;
      __syncthreads();
      if (kb + 64 < K) {
        pa0 = *(const int4*)(Ag0 + kb + 64); pa1 = *(const int4*)(Ag0 + kb + 72);
        pa2 = *(const int4*)(Ag1 + kb + 64); pa3 = *(const int4*)(Ag1 + kb + 72);
        pb0 = *(const int4*)(Bg0 + kb + 64); pb1 = *(const int4*)(Bg0 + kb + 72);
        pb2 = *(const int4*)(Bg1 + kb + 64); pb3 = *(const int4*)(Bg1 + kb + 72);
      }
#pragma unroll
      for (int ks = 0; ks < 2; ++ks) {
        bf16x8 af[2], bf[4];
#pragma unroll
        for (int mi = 0; mi < 2; ++mi)
          af[mi] = *(const bf16x8*)&As[(wr + mi * 16 + lm) * 72 + ks * 32 + koff];
#pragma unroll
        for (int ni = 0; ni < 4; ++ni)
          bf[ni] = *(const bf16x8*)&Bs[(ni * 16 + lm) * 72 + ks * 32 + koff];
#pragma unroll
        for (int mi = 0; mi < 2; ++mi)
#pragma unroll
          for (int ni = 0; ni < 4; ++ni)
            acc[mi][ni] = __builtin_amdgcn_mfma_f32_16x16x32_bf16(af[mi], bf[ni], acc[mi][ni], 0, 0, 0);
      }
    }

#pragma unroll
    for (int mi = 0; mi < 2; ++mi) {
#pragma unroll
      for (int ni = 0; ni < 4; ++ni) {
        const int gc = n0 + ni * 16 + lm;
        const float bv = bias[gc];
#pragma unroll
        for (int r = 0; r < 4; ++r) {
          const int gr = m0 + wr + mi * 16 + q4 + r;
          float v = acc[mi][ni][r] + bv;
          if (RELU) v = fmaxf(v, 0.f);
          if (SCALE) v *= scale[gr];
          if (F32OUT) {
            if (gr < N_NODES) Cf[(size_t)gr * ldc + gc] = v;
          } else {
            Cb[(size_t)gr * ldc + gc] = f2b(v);
          }
        }
      }
    }
    __syncthreads();   // As/Bs reused next tile
  }
}

// ------------------------------------------------------- aggregate phase ----
// One WAVE per node; paired gather (half-wave per neighbor, uint4/lane),
// unroll 4 -> 8 neighbors in flight; cross-half __shfl reduce.
__device__ void agg_phase(const u16* __restrict__ tmp, const int* __restrict__ row_ptr,
                          const int* __restrict__ csr, u16* __restrict__ out0,
                          u16* __restrict__ cat1, u16* __restrict__ cat2, int mode,
                          int bid, int nb, int tid) {
  const int wave = tid >> 6;
  const int lane = tid & 63;
  const int half = lane >> 5;
  const int q = lane & 31;
  const size_t feat = (size_t)q * 16;
  const char* tb = (const char*)tmp;

  for (int r = bid * 2 + wave; r < N_NODES; r += nb * 2) {
    const int beg = row_ptr[r], end = row_ptr[r + 1];
    float s0 = 0.f, s1 = 0.f, s2 = 0.f, s3 = 0.f, s4 = 0.f, s5 = 0.f, s6 = 0.f, s7 = 0.f;
    int i = beg;
    for (; i + 8 <= end; i += 8) {
      uint4 v[4];
#pragma unroll
      for (int j = 0; j < 4; ++j)
        v[j] = *(const uint4*)(tb + (size_t)csr[i + 2 * j + half] * 512 + feat);
#pragma unroll
      for (int j = 0; j < 4; ++j) {
        s0 += blo(v[j].x); s1 += bhi(v[j].x); s2 += blo(v[j].y); s3 += bhi(v[j].y);
        s4 += blo(v[j].z); s5 += bhi(v[j].z); s6 += blo(v[j].w); s7 += bhi(v[j].w);
      }
    }
    for (; i < end; i += 2) {
      int id = i + half;
      if (id < end) {
        uint4 v = *(const uint4*)(tb + (size_t)csr[id] * 512 + feat);
        s0 += blo(v.x); s1 += bhi(v.x); s2 += blo(v.y); s3 += bhi(v.y);
        s4 += blo(v.z); s5 += bhi(v.z); s6 += blo(v.w); s7 += bhi(v.w);
      }
    }
    const int src = lane ^ 32;
    s0 += __shfl(s0, src, 64); s1 += __shfl(s1, src, 64);
    s2 += __shfl(s2, src, 64); s3 += __shfl(s3, src, 64);
    s4 += __shfl(s4, src, 64); s5 += __shfl(s5, src, 64);
    s6 += __shfl(s6, src, 64); s7 += __shfl(s7, src, 64);

    if (half == 0) {
      uint4 pv;
      pv.x = pack2(s0, s1); pv.y = pack2(s2, s3);
      pv.z = pack2(s4, s5); pv.w = pack2(s6, s7);
      if (mode == 0) {
        *(uint4*)((char*)out0 + (size_t)r * 512 + feat) = pv;
      } else {
        uint4 pr;
        pr.x = pack2(fmaxf(s0, 0.f), fmaxf(s1, 0.f));
        pr.y = pack2(fmaxf(s2, 0.f), fmaxf(s3, 0.f));
        pr.z = pack2(fmaxf(s4, 0.f), fmaxf(s5, 0.f));
        pr.w = pack2(fmaxf(s6, 0.f), fmaxf(s7, 0.f));
        *(uint4*)((char*)cat1 + (size_t)r * 1024 + feat) = pr;          // relu(h3)
        *(uint4*)((char*)cat1 + (size_t)r * 1024 + 512 + feat) = pv;    // h3
        *(uint4*)((char*)cat2 + (size_t)r * 1536 + 1024 + feat) = pv;   // h3 tail
      }
    }
  }
}

// --------------------------------------------------------------- compute ----
// ONE cooperative kernel: G1-A1-G2-A2-G3-A3-FC1-FC2-OUT with grid syncs.
__global__ __launch_bounds__(128) void compute(CP P) {
  __shared__ u16 As[64 * 72];
  __shared__ u16 Bs[64 * 72];
  cg::grid_group grid = cg::this_grid();
  const int tid = threadIdx.x, bid = blockIdx.x, nb = gridDim.x;

  gemm_phase<256, true, true, false>(158, 4, P.xb, 256, P.w0t, P.mp_b0, P.deg_inv,
                                     P.tmp, nullptr, 256, As, Bs, bid, nb, tid);
  grid.sync();
  agg_phase(P.tmp, P.row_ptr, P.csr, P.h, nullptr, nullptr, 0, bid, nb, tid);
  grid.sync();
  gemm_phase<256, true, true, false>(158, 4, P.h, 256, P.w1t, P.mp_b1, P.deg_inv,
                                     P.tmp, nullptr, 256, As, Bs, bid, nb, tid);
  grid.sync();
  agg_phase(P.tmp, P.row_ptr, P.csr, P.h, nullptr, nullptr, 0, bid, nb, tid);
  grid.sync();
  gemm_phase<256, true, true, false>(158, 4, P.h, 256, P.w2t, P.mp_b2, P.deg_inv,
                                     P.tmp, nullptr, 256, As, Bs, bid, nb, tid);
  grid.sync();
  agg_phase(P.tmp, P.row_ptr, P.csr, nullptr, P.cat1, P.cat2, 1, bid, nb, tid);
  grid.sync();
  gemm_phase<512, true, false, false>(158, 8, P.cat1, 512, P.wc1t, P.bias1, nullptr,
                                      P.cat2, nullptr, 768, As, Bs, bid, nb, tid);
  grid.sync();
  gemm_phase<768, false, false, false>(158, 8, P.cat2, 768, P.wc2t, P.bias2, nullptr,
                                       P.C2, nullptr, 512, As, Bs, bid, nb, tid);
  grid.sync();
  gemm_phase<512, false, false, true>(158, 1, P.C2, 512, P.owt, P.out_b, nullptr,
                                      nullptr, P.out, 64, As, Bs, bid, nb, tid);
}

// -------------------------------------------------------------- launch ------
extern "C" void kernel_launch(void* const* d_in, const int* in_sizes, int n_in,
                              void* d_out, int out_size, void* d_ws, size_t ws_size,
                              hipStream_t stream) {
  char* p = (char*)d_ws;
  auto carve = [&](size_t bytes) -> void* {
    void* r = (void*)p;
    p += (bytes + 255) & ~(size_t)255;
    return r;
  };
  int*   histR    = (int*)carve((size_t)NCH * NBIN * 4);
  int*   histC    = (int*)carve((size_t)NCH * NBIN * 4);
  int*   chunkoff = (int*)carve((size_t)NCH * NBIN * 4);
  int*   cntR     = (int*)carve(NBIN * 4);
  int*   row_ptr  = (int*)carve((N_NODES + 1) * 4);
  int*   csr      = (int*)carve((size_t)N_EDGES * 4);
  float* deg_inv  = (float*)carve(MPAD * 4);
  float* bias1    = (float*)carve(512 * 4);
  float* bias2    = (float*)carve(512 * 4);
  u16* xb   = (u16*)carve((size_t)MPAD * 256 * 2);
  u16* w0t  = (u16*)carve(65536 * 2);
  u16* w1t  = (u16*)carve(65536 * 2);
  u16* w2t  = (u16*)carve(65536 * 2);
  u16* wc1t = (u16*)carve(262144 * 2);
  u16* wc2t = (u16*)carve(393216 * 2);
  u16* owt  = (u16*)carve(32768 * 2);
  u16* tmp  = (u16*)carve((size_t)MPAD * 256 * 2);
  u16* h    = (u16*)carve((size_t)MPAD * 256 * 2);
  u16* cat1 = (u16*)carve((size_t)MPAD * 512 * 2);
  u16* cat2 = (u16*)carve((size_t)MPAD * 768 * 2);
  u16* C2   = (u16*)carve((size_t)MPAD * 512 * 2);

  PP pp;
  pp.x = (const float*)d_in[0];
  pp.ei = (const int*)d_in[1];        // int inputs arrive as int32
  pp.w0 = (const float*)d_in[2];
  pp.w1 = (const float*)d_in[4];
  pp.w2 = (const float*)d_in[6];
  pp.fcw0 = (const float*)d_in[8];
  pp.fcw1 = (const float*)d_in[10];
  pp.injw0 = (const float*)d_in[12];
  pp.injw1 = (const float*)d_in[14];
  pp.outw = (const float*)d_in[17];
  pp.fcb0 = (const float*)d_in[9];
  pp.injb0 = (const float*)d_in[13];
  pp.fcb1 = (const float*)d_in[11];
  pp.injb1 = (const float*)d_in[15];
  pp.alpha = (const float*)d_in[16];
  pp.xb = xb; pp.w0t = w0t; pp.w1t = w1t; pp.w2t = w2t;
  pp.wc1t = wc1t; pp.wc2t = wc2t; pp.owt = owt;
  pp.bias1 = bias1; pp.bias2 = bias2;
  pp.histR = histR; pp.histC = histC; pp.chunkoff = chunkoff;
  pp.cntR = cntR; pp.row_ptr = row_ptr; pp.csr = csr; pp.deg_inv = deg_inv;

  CP cp;
  cp.xb = xb; cp.w0t = w0t; cp.w1t = w1t; cp.w2t = w2t;
  cp.wc1t = wc1t; cp.wc2t = wc2t; cp.owt = owt;
  cp.mp_b0 = (const float*)d_in[3];
  cp.mp_b1 = (const float*)d_in[5];
  cp.mp_b2 = (const float*)d_in[7];
  cp.bias1 = bias1; cp.bias2 = bias2;
  cp.out_b = (const float*)d_in[18];
  cp.deg_inv = deg_inv;
  cp.row_ptr = row_ptr; cp.csr = csr;
  cp.tmp = tmp; cp.h = h; cp.cat1 = cat1; cp.cat2 = cat2; cp.C2 = C2;
  cp.out = (float*)d_out;

  // grid = co-resident capacity (cooperative-launch requirement)
  int occ1 = 0, occ2 = 0;
  hipOccupancyMaxActiveBlocksPerMultiprocessor(&occ1, prolog, 256, 0);
  hipOccupancyMaxActiveBlocksPerMultiprocessor(&occ2, compute, 128, 0);
  if (occ1 < 1) occ1 = 1;
  if (occ2 < 1) occ2 = 1;
  int g1 = occ1 * 256;
  int g2 = occ2 * 256;

  void* a1[] = { &pp };
  void* a2[] = { &cp };
  hipLaunchCooperativeKernel((const void*)prolog, dim3(g1), dim3(256), a1, 0, stream);
  hipLaunchCooperativeKernel((const void*)compute, dim3(g2), dim3(128), a2, 0, stream);
}

// Round 9
// 265.444 us; speedup vs baseline: 4.0209x; 4.0209x over previous
//
#include <hip/hip_runtime.h>

#define N_NODES 10000
#define N_EDGES 320000
#define MPAD 10112   // 158 * 64
#define NBIN 10048
#define CHUNK 2048
#define NCH 157      // ceil(E / CHUNK)
#define PREP_BLOCKS 259
#define PREP_TOT 1148480L

typedef unsigned short u16;
typedef short bf16x8 __attribute__((ext_vector_type(8)));
typedef float f32x4 __attribute__((ext_vector_type(4)));

__device__ __forceinline__ u16 f2b(float f) {
  unsigned u = __builtin_bit_cast(unsigned, f);
  unsigned r = u + 0x7fffu + ((u >> 16) & 1u);
  return (u16)(r >> 16);
}
__device__ __forceinline__ unsigned pack2(float a, float b) {
  return (unsigned)f2b(a) | ((unsigned)f2b(b) << 16);
}
__device__ __forceinline__ float blo(unsigned u) { return __builtin_bit_cast(float, u << 16); }
__device__ __forceinline__ float bhi(unsigned u) { return __builtin_bit_cast(float, u & 0xffff0000u); }

// ---------------------------------------------------------- param struct ----
struct PP {
  const float *x; const int *ei;
  const float *w0, *w1, *w2, *fcw0, *injw0, *fcw1, *injw1, *outw;
  const float *fcb0, *injb0, *fcb1, *injb1, *alpha, *outb;
  u16 *xb, *w0t, *w1t, *w2t, *wc1t, *wft;
  float *bias1, *bf;
  int *histR, *histC;
};

// ------------------------------------------------------- prep + edge_hist ---
// Blocks 0..NCH-1: per-chunk LDS histograms (deterministic CSR step 1).
// Blocks NCH..NCH+PREP_BLOCKS-1: grid-stride prep items:
//   x->bf16, W^T casts, fused Wcat1, and the FC2+out FOLD:
//   Wf = Wcat2 @ out_w (fp32, from raw inputs), bf = bias2 @ out_w + out_b.
// All writes are pure functions of d_in -> replay-safe.
__global__ __launch_bounds__(256) void prep_hist(PP P) {
  __shared__ int sh[2 * NBIN];   // 80.4 KB (gfx950 allows >64KB; proven R4-R7)
  const int tid = threadIdx.x, bid = blockIdx.x;
  const float alpha = P.alpha[0];

  if (bid < NCH) {  // ---- histogram chunk
    for (int i = tid; i < 2 * NBIN; i += 256) sh[i] = 0;
    __syncthreads();
    const int e0 = bid * CHUNK;
    for (int j = tid; j < CHUNK; j += 256) {
      int e = e0 + j;
      if (e < N_EDGES) {
        atomicAdd(&sh[P.ei[e]], 1);
        atomicAdd(&sh[NBIN + P.ei[N_EDGES + e]], 1);
      }
    }
    __syncthreads();
    for (int i = tid; i < NBIN; i += 256) {
      P.histR[(size_t)bid * NBIN + i] = sh[i];
      P.histC[(size_t)bid * NBIN + i] = sh[NBIN + i];
    }
    return;
  }

  // ---- prep items, grid-stride
  const long stride = (long)PREP_BLOCKS * 256;
  for (long ii = (long)(bid - NCH) * 256 + tid; ii < PREP_TOT; ii += stride) {
    long i = ii;
    if (i < 640000L) {  // x -> bf16, 4 floats per item
      float4 v = ((const float4*)P.x)[i];
      uint2 o;
      o.x = pack2(v.x, v.y);
      o.y = pack2(v.z, v.w);
      *(uint2*)(P.xb + 4 * i) = o;
      continue;
    }
    i -= 640000L;
    if (i < 65536) { P.w0t[i] = f2b(P.w0[(i & 255) * 256 + (i >> 8)]); continue; }
    i -= 65536;
    if (i < 65536) { P.w1t[i] = f2b(P.w1[(i & 255) * 256 + (i >> 8)]); continue; }
    i -= 65536;
    if (i < 65536) { P.w2t[i] = f2b(P.w2[(i & 255) * 256 + (i >> 8)]); continue; }
    i -= 65536;
    if (i < 262144) {  // Wcat1^T [512 n][512 k]: k<256 -> alpha*fc_w0 ; else inj_w0
      int n = (int)(i >> 9), k = (int)(i & 511);
      float v = (k < 256) ? alpha * P.fcw0[k * 512 + n] : P.injw0[(k - 256) * 512 + n];
      P.wc1t[i] = f2b(v); continue;
    }
    i -= 262144;
    if (i < 49152) {   // Wf^T [64 n][768 k] = (Wcat2 @ out_w)^T, fp32 accumulate
      int n = (int)(i & 63), k = (int)(i >> 6);
      float acc = 0.f;
      if (k < 512) {
        const float* fr = P.fcw1 + (size_t)k * 512;
#pragma unroll 8
        for (int j = 0; j < 512; ++j) acc += fr[j] * P.outw[j * 64 + n];
        acc *= alpha;
      } else {
        const float* ir = P.injw1 + (size_t)(k - 512) * 512;
#pragma unroll 8
        for (int j = 0; j < 512; ++j) acc += ir[j] * P.outw[j * 64 + n];
      }
      P.wft[n * 768 + k] = f2b(acc);
      continue;
    }
    i -= 49152;
    if (i < 64) {      // bf = bias2 @ out_w + out_b (bias2 = alpha*fcb1+injb1)
      float acc = P.outb[i];
#pragma unroll 8
      for (int j = 0; j < 512; ++j)
        acc += (alpha * P.fcb1[j] + P.injb1[j]) * P.outw[j * 64 + i];
      P.bf[i] = acc;
      continue;
    }
    i -= 64;
    if (i < 512) { P.bias1[i] = alpha * P.fcb0[i] + P.injb0[i]; continue; }
  }
}

// ----------------------------------------------------------- CSR build ------
// per-bin scan across chunks -> chunkoff, cntR, deg_inv (covers MPAD pad=1.0)
__global__ __launch_bounds__(256) void col_scan(const int* __restrict__ histR,
                                                const int* __restrict__ histC,
                                                int* __restrict__ chunkoff,
                                                int* __restrict__ cntR,
                                                float* __restrict__ deg_inv) {
  int r = blockIdx.x * 256 + threadIdx.x;
  if (r >= MPAD) return;
  if (r >= NBIN) { deg_inv[r] = 1.0f; return; }
  int run = 0, dg = 0;
#pragma unroll 4
  for (int ch = 0; ch < NCH; ++ch) {
    chunkoff[(size_t)ch * NBIN + r] = run;
    run += histR[(size_t)ch * NBIN + r];
    dg  += histC[(size_t)ch * NBIN + r];
  }
  cntR[r] = run;
  deg_inv[r] = 1.0f / (float)(dg > 1 ? dg : 1);
}

__global__ __launch_bounds__(1024) void row_scan(const int* __restrict__ cntR,
                                                 int* __restrict__ row_ptr) {
  const int t = threadIdx.x;
  const int i0 = t * 10;
  int v[10];
  int s = 0;
#pragma unroll
  for (int i = 0; i < 10; ++i) {
    int id = i0 + i;
    v[i] = (id < NBIN) ? cntR[id] : 0;
    s += v[i];
  }
  int lane = t & 63, wid = t >> 6;
  int incl = s;
#pragma unroll
  for (int off = 1; off < 64; off <<= 1) {
    int y = __shfl_up(incl, off, 64);
    if (lane >= off) incl += y;
  }
  __shared__ int wsum[16], wexc[16];
  if (lane == 63) wsum[wid] = incl;
  __syncthreads();
  if (t == 0) {
    int run = 0;
#pragma unroll
    for (int i = 0; i < 16; ++i) { wexc[i] = run; run += wsum[i]; }
  }
  __syncthreads();
  int run = wexc[wid] + incl - s;
#pragma unroll
  for (int i = 0; i < 10; ++i) {
    int id = i0 + i;
    if (id <= N_NODES) row_ptr[id] = run;
    run += v[i];
  }
}

__global__ __launch_bounds__(256) void place_edges(const int* __restrict__ ei,
                                                   const int* __restrict__ chunkoff,
                                                   const int* __restrict__ row_ptr,
                                                   int* __restrict__ csr) {
  __shared__ int cur[NBIN];
  const int ch = blockIdx.x, t = threadIdx.x;
  const int* co = chunkoff + (size_t)ch * NBIN;
  for (int i = t; i < NBIN; i += 256) cur[i] = co[i];
  __syncthreads();
  const int e0 = ch * CHUNK;
#pragma unroll
  for (int j = 0; j < CHUNK; j += 256) {
    int e = e0 + j + t;
    if (e < N_EDGES) {
      int r = ei[e];
      int c = ei[N_EDGES + e];
      int rank = atomicAdd(&cur[r], 1);   // LDS only; disjoint slots across chunks
      csr[row_ptr[r] + rank] = c;
    }
  }
}

// ---------------------------------------------------------------- GEMM ------
// 64x64 tile, TWO waves per block (128 threads): each wave computes 32x64
// (2x4 MFMA 16x16x32 frags). Proven R7 config (~8 blocks/CU resident).
template<int K, bool RELU, bool SCALE, bool F32OUT>
__global__ __launch_bounds__(128) void gemm64(
    const u16* __restrict__ A, int lda,
    const u16* __restrict__ Bt,
    const float* __restrict__ bias,
    const float* __restrict__ scale,
    u16* __restrict__ Cb, float* __restrict__ Cf, int ldc)
{
  __shared__ u16 As[64 * 72];
  __shared__ u16 Bs[64 * 72];
  const int tid = threadIdx.x;
  const int m0 = blockIdx.x * 64;
  const int n0 = blockIdx.y * 64;
  const int wave = tid >> 6;
  const int lane = tid & 63;
  const int wr = wave * 32;
  const int lm = lane & 15;
  const int koff = (lane >> 4) * 8;

  const int srow = tid >> 2;          // stages rows srow and srow+32
  const int scol = (tid & 3) * 16;    // 16 u16 per row = 2 int4
  const u16* Ag0 = A + (size_t)(m0 + srow) * lda + scol;
  const u16* Ag1 = A + (size_t)(m0 + srow + 32) * lda + scol;
  const u16* Bg0 = Bt + (size_t)(n0 + srow) * K + scol;
  const u16* Bg1 = Bt + (size_t)(n0 + srow + 32) * K + scol;
  u16* Asw0 = &As[srow * 72 + scol];
  u16* Asw1 = &As[(srow + 32) * 72 + scol];
  u16* Bsw0 = &Bs[srow * 72 + scol];
  u16* Bsw1 = &Bs[(srow + 32) * 72 + scol];

  f32x4 acc[2][4] = {};

  int4 pa0 = *(const int4*)(Ag0),     pa1 = *(const int4*)(Ag0 + 8);
  int4 pa2 = *(const int4*)(Ag1),     pa3 = *(const int4*)(Ag1 + 8);
  int4 pb0 = *(const int4*)(Bg0),     pb1 = *(const int4*)(Bg0 + 8);
  int4 pb2 = *(const int4*)(Bg1),     pb3 = *(const int4*)(Bg1 + 8);

#pragma unroll
  for (int kb = 0; kb < K; kb += 64) {
    __syncthreads();
    *(int4*)Asw0 = pa0; *(int4*)(Asw0 + 8) = pa1;
    *(int4*)Asw1 = pa2; *(int4*)(Asw1 + 8) = pa3;
    *(int4*)Bsw0 = pb0; *(int4*)(Bsw0 + 8) = pb1;
    *(int4*)Bsw1 = pb2; *(int4*)(Bsw1 + 8) = pb3;
    __syncthreads();
    if (kb + 64 < K) {
      pa0 = *(const int4*)(Ag0 + kb + 64); pa1 = *(const int4*)(Ag0 + kb + 72);
      pa2 = *(const int4*)(Ag1 + kb + 64); pa3 = *(const int4*)(Ag1 + kb + 72);
      pb0 = *(const int4*)(Bg0 + kb + 64); pb1 = *(const int4*)(Bg0 + kb + 72);
      pb2 = *(const int4*)(Bg1 + kb + 64); pb3 = *(const int4*)(Bg1 + kb + 72);
    }
#pragma unroll
    for (int ks = 0; ks < 2; ++ks) {
      bf16x8 af[2], bf[4];
#pragma unroll
      for (int mi = 0; mi < 2; ++mi)
        af[mi] = *(const bf16x8*)&As[(wr + mi * 16 + lm) * 72 + ks * 32 + koff];
#pragma unroll
      for (int ni = 0; ni < 4; ++ni)
        bf[ni] = *(const bf16x8*)&Bs[(ni * 16 + lm) * 72 + ks * 32 + koff];
#pragma unroll
      for (int mi = 0; mi < 2; ++mi)
#pragma unroll
        for (int ni = 0; ni < 4; ++ni)
          acc[mi][ni] = __builtin_amdgcn_mfma_f32_16x16x32_bf16(af[mi], bf[ni], acc[mi][ni], 0, 0, 0);
    }
  }

  const int q4 = (lane >> 4) * 4;
#pragma unroll
  for (int mi = 0; mi < 2; ++mi) {
#pragma unroll
    for (int ni = 0; ni < 4; ++ni) {
      const int gc = n0 + ni * 16 + lm;
      const float bv = bias[gc];
#pragma unroll
      for (int r = 0; r < 4; ++r) {
        const int gr = m0 + wr + mi * 16 + q4 + r;
        float v = acc[mi][ni][r] + bv;
        if (RELU) v = fmaxf(v, 0.f);
        if (SCALE) v *= scale[gr];
        if (F32OUT) {
          if (gr < N_NODES) Cf[(size_t)gr * ldc + gc] = v;
        } else {
          Cb[(size_t)gr * ldc + gc] = f2b(v);
        }
      }
    }
  }
}

// ----------------------------------------------------------- aggregate ------
// One WAVE per node; paired gather: half-wave per neighbor, uint4/lane,
// unroll 4 -> 8 neighbors in flight; cross-half __shfl reduce. (R7 proven)
__global__ __launch_bounds__(256) void aggregate(
    const u16* __restrict__ tmp, const int* __restrict__ row_ptr,
    const int* __restrict__ csr, u16* __restrict__ out0,
    u16* __restrict__ A1, u16* __restrict__ A2, int mode)
{
  const int wv = threadIdx.x >> 6;
  const int lane = threadIdx.x & 63;
  const int r = blockIdx.x * 4 + wv;          // grid = 2500 -> r in [0,10000)
  const int half = lane >> 5;
  const int q = lane & 31;
  const int beg = row_ptr[r], end = row_ptr[r + 1];
  const size_t feat = (size_t)q * 16;
  const char* tb = (const char*)tmp;

  float s0 = 0.f, s1 = 0.f, s2 = 0.f, s3 = 0.f, s4 = 0.f, s5 = 0.f, s6 = 0.f, s7 = 0.f;
  int i = beg;
  for (; i + 8 <= end; i += 8) {
    uint4 v[4];
#pragma unroll
    for (int j = 0; j < 4; ++j)
      v[j] = *(const uint4*)(tb + (size_t)csr[i + 2 * j + half] * 512 + feat);
#pragma unroll
    for (int j = 0; j < 4; ++j) {
      s0 += blo(v[j].x); s1 += bhi(v[j].x); s2 += blo(v[j].y); s3 += bhi(v[j].y);
      s4 += blo(v[j].z); s5 += bhi(v[j].z); s6 += blo(v[j].w); s7 += bhi(v[j].w);
    }
  }
  for (; i < end; i += 2) {
    int id = i + half;
    if (id < end) {
      uint4 v = *(const uint4*)(tb + (size_t)csr[id] * 512 + feat);
      s0 += blo(v.x); s1 += bhi(v.x); s2 += blo(v.y); s3 += bhi(v.y);
      s4 += blo(v.z); s5 += bhi(v.z); s6 += blo(v.w); s7 += bhi(v.w);
    }
  }
  const int src = lane ^ 32;
  s0 += __shfl(s0, src, 64); s1 += __shfl(s1, src, 64);
  s2 += __shfl(s2, src, 64); s3 += __shfl(s3, src, 64);
  s4 += __shfl(s4, src, 64); s5 += __shfl(s5, src, 64);
  s6 += __shfl(s6, src, 64); s7 += __shfl(s7, src, 64);

  if (half == 0) {
    uint4 pv;
    pv.x = pack2(s0, s1); pv.y = pack2(s2, s3);
    pv.z = pack2(s4, s5); pv.w = pack2(s6, s7);
    if (mode == 0) {
      *(uint4*)((char*)out0 + (size_t)r * 512 + feat) = pv;
    } else {
      uint4 pr;
      pr.x = pack2(fmaxf(s0, 0.f), fmaxf(s1, 0.f));
      pr.y = pack2(fmaxf(s2, 0.f), fmaxf(s3, 0.f));
      pr.z = pack2(fmaxf(s4, 0.f), fmaxf(s5, 0.f));
      pr.w = pack2(fmaxf(s6, 0.f), fmaxf(s7, 0.f));
      *(uint4*)((char*)A1 + (size_t)r * 1024 + feat) = pr;          // relu(h3)
      *(uint4*)((char*)A1 + (size_t)r * 1024 + 512 + feat) = pv;    // h3
      *(uint4*)((char*)A2 + (size_t)r * 1536 + 1024 + feat) = pv;   // h3 tail
    }
  }
}

// -------------------------------------------------------------- launch ------
extern "C" void kernel_launch(void* const* d_in, const int* in_sizes, int n_in,
                              void* d_out, int out_size, void* d_ws, size_t ws_size,
                              hipStream_t stream) {
  const int* ei = (const int*)d_in[1];   // int inputs arrive as int32

  char* p = (char*)d_ws;
  auto carve = [&](size_t bytes) -> void* {
    void* r = (void*)p;
    p += (bytes + 255) & ~(size_t)255;
    return r;
  };
  int*   histR    = (int*)carve((size_t)NCH * NBIN * 4);
  int*   histC    = (int*)carve((size_t)NCH * NBIN * 4);
  int*   chunkoff = (int*)carve((size_t)NCH * NBIN * 4);
  int*   cntR     = (int*)carve(NBIN * 4);
  int*   row_ptr  = (int*)carve((N_NODES + 1) * 4);
  int*   csr      = (int*)carve((size_t)N_EDGES * 4);
  float* deg_inv  = (float*)carve(MPAD * 4);
  float* bias1    = (float*)carve(512 * 4);
  float* bf       = (float*)carve(64 * 4);
  u16* xb   = (u16*)carve((size_t)MPAD * 256 * 2);
  u16* w0t  = (u16*)carve(65536 * 2);
  u16* w1t  = (u16*)carve(65536 * 2);
  u16* w2t  = (u16*)carve(65536 * 2);
  u16* wc1t = (u16*)carve(262144 * 2);
  u16* wft  = (u16*)carve(49152 * 2);
  u16* tmp  = (u16*)carve((size_t)MPAD * 256 * 2);
  u16* h    = (u16*)carve((size_t)MPAD * 256 * 2);
  u16* cat1 = (u16*)carve((size_t)MPAD * 512 * 2);
  u16* cat2 = (u16*)carve((size_t)MPAD * 768 * 2);

  PP pp;
  pp.x = (const float*)d_in[0];
  pp.ei = ei;
  pp.w0 = (const float*)d_in[2];
  pp.w1 = (const float*)d_in[4];
  pp.w2 = (const float*)d_in[6];
  pp.fcw0 = (const float*)d_in[8];
  pp.fcw1 = (const float*)d_in[10];
  pp.injw0 = (const float*)d_in[12];
  pp.injw1 = (const float*)d_in[14];
  pp.outw = (const float*)d_in[17];
  pp.fcb0 = (const float*)d_in[9];
  pp.injb0 = (const float*)d_in[13];
  pp.fcb1 = (const float*)d_in[11];
  pp.injb1 = (const float*)d_in[15];
  pp.alpha = (const float*)d_in[16];
  pp.outb = (const float*)d_in[18];
  pp.xb = xb; pp.w0t = w0t; pp.w1t = w1t; pp.w2t = w2t;
  pp.wc1t = wc1t; pp.wft = wft;
  pp.bias1 = bias1; pp.bf = bf;
  pp.histR = histR; pp.histC = histC;

  const float* mp_b0 = (const float*)d_in[3];
  const float* mp_b1 = (const float*)d_in[5];
  const float* mp_b2 = (const float*)d_in[7];
  float* out = (float*)d_out;

  prep_hist<<<NCH + PREP_BLOCKS, 256, 0, stream>>>(pp);
  col_scan<<<(MPAD + 255) / 256, 256, 0, stream>>>(histR, histC, chunkoff, cntR, deg_inv);
  row_scan<<<1, 1024, 0, stream>>>(cntR, row_ptr);
  place_edges<<<NCH, 256, 0, stream>>>(ei, chunkoff, row_ptr, csr);

  dim3 gmp(MPAD / 64, 4), gfc(MPAD / 64, 8), go(MPAD / 64, 1);
  // MP layer 1..3: tmp = relu(h @ W + b) * deg_inv ; h' = CSR-aggregate(tmp)
  gemm64<256, true, true, false><<<gmp, 128, 0, stream>>>(xb, 256, w0t, mp_b0, deg_inv, tmp, nullptr, 256);
  aggregate<<<2500, 256, 0, stream>>>(tmp, row_ptr, csr, h, nullptr, nullptr, 0);
  gemm64<256, true, true, false><<<gmp, 128, 0, stream>>>(h, 256, w1t, mp_b1, deg_inv, tmp, nullptr, 256);
  aggregate<<<2500, 256, 0, stream>>>(tmp, row_ptr, csr, h, nullptr, nullptr, 0);
  gemm64<256, true, true, false><<<gmp, 128, 0, stream>>>(h, 256, w2t, mp_b2, deg_inv, tmp, nullptr, 256);
  aggregate<<<2500, 256, 0, stream>>>(tmp, row_ptr, csr, nullptr, cat1, cat2, 1);
  // FC1 (+inj0 fused, K=512) -> relu -> cat2[:, 0:512]
  gemm64<512, true, false, false><<<gfc, 128, 0, stream>>>(cat1, 512, wc1t, bias1, nullptr, cat2, nullptr, 768);
  // FOLDED: out = cat2 @ (Wcat2 @ out_w) + (bias2 @ out_w + out_b), fp32 store
  gemm64<768, false, false, true><<<go, 128, 0, stream>>>(cat2, 768, wft, bf, nullptr, nullptr, out, 64);
}

// Round 10
// 245.083 us; speedup vs baseline: 4.3549x; 1.0831x over previous
//
#include <hip/hip_runtime.h>

#define N_NODES 10000
#define N_EDGES 320000
#define MPAD 10112   // 158 * 64
#define NBIN 10048
#define CHUNK 2048
#define NCH 157      // ceil(E / CHUNK)
#define CAP 128      // fixed CSR row capacity (max degree ~55 expected, 17-sigma margin)
#define PREP_BLOCKS 512
#define PREP_TOT 1148480L

typedef unsigned short u16;
typedef short bf16x8 __attribute__((ext_vector_type(8)));
typedef float f32x4 __attribute__((ext_vector_type(4)));

__device__ __forceinline__ u16 f2b(float f) {
  unsigned u = __builtin_bit_cast(unsigned, f);
  unsigned r = u + 0x7fffu + ((u >> 16) & 1u);
  return (u16)(r >> 16);
}
__device__ __forceinline__ unsigned pack2(float a, float b) {
  return (unsigned)f2b(a) | ((unsigned)f2b(b) << 16);
}
__device__ __forceinline__ float blo(unsigned u) { return __builtin_bit_cast(float, u << 16); }
__device__ __forceinline__ float bhi(unsigned u) { return __builtin_bit_cast(float, u & 0xffff0000u); }

// ---------------------------------------------------------- param struct ----
struct PP {
  const float *x; const int *ei;
  const float *w0, *w1, *w2, *fcw0, *injw0, *fcw1, *injw1, *outw;
  const float *fcb0, *injb0, *fcb1, *injb1, *alpha, *outb;
  u16 *xb, *w0t, *w1t, *w2t, *wc1t, *wft;
  float *bias1, *bf;
  unsigned *histRC;
};

// ------------------------------------------------------- prep + edge_hist ---
// Blocks 0..NCH-1: per-chunk PACKED histograms (R in low16, C in high16;
// chunk=2048 edges so no overflow). 40KB LDS -> 4 blocks/CU (R9 post-mortem:
// the 80KB two-array version strangled the whole kernel to 2 blocks/CU,
// 9.8% occupancy, 44us).
// Blocks NCH..: grid-stride prep items (x->bf16, W^T casts, fused Wcat1,
// FC2+out fold Wf=Wcat2@out_w). Pure function of d_in -> replay-safe.
__global__ __launch_bounds__(256) void prep_hist(PP P) {
  __shared__ unsigned sh[NBIN];   // 40.2 KB packed
  const int tid = threadIdx.x, bid = blockIdx.x;
  const float alpha = P.alpha[0];

  if (bid < NCH) {  // ---- histogram chunk
    for (int i = tid; i < NBIN; i += 256) sh[i] = 0;
    __syncthreads();
    const int e0 = bid * CHUNK;
    for (int j = tid; j < CHUNK; j += 256) {
      int e = e0 + j;
      if (e < N_EDGES) {
        atomicAdd(&sh[P.ei[e]], 1u);                 // row (scatter dest)
        atomicAdd(&sh[P.ei[N_EDGES + e]], 65536u);   // col (deg source)
      }
    }
    __syncthreads();
    for (int i = tid; i < NBIN; i += 256)
      P.histRC[(size_t)bid * NBIN + i] = sh[i];
    return;
  }

  // ---- prep items, grid-stride
  const long stride = (long)PREP_BLOCKS * 256;
  for (long ii = (long)(bid - NCH) * 256 + tid; ii < PREP_TOT; ii += stride) {
    long i = ii;
    if (i < 640000L) {  // x -> bf16, 4 floats per item
      float4 v = ((const float4*)P.x)[i];
      uint2 o;
      o.x = pack2(v.x, v.y);
      o.y = pack2(v.z, v.w);
      *(uint2*)(P.xb + 4 * i) = o;
      continue;
    }
    i -= 640000L;
    if (i < 65536) { P.w0t[i] = f2b(P.w0[(i & 255) * 256 + (i >> 8)]); continue; }
    i -= 65536;
    if (i < 65536) { P.w1t[i] = f2b(P.w1[(i & 255) * 256 + (i >> 8)]); continue; }
    i -= 65536;
    if (i < 65536) { P.w2t[i] = f2b(P.w2[(i & 255) * 256 + (i >> 8)]); continue; }
    i -= 65536;
    if (i < 262144) {  // Wcat1^T [512 n][512 k]: k<256 -> alpha*fc_w0 ; else inj_w0
      int n = (int)(i >> 9), k = (int)(i & 511);
      float v = (k < 256) ? alpha * P.fcw0[k * 512 + n] : P.injw0[(k - 256) * 512 + n];
      P.wc1t[i] = f2b(v); continue;
    }
    i -= 262144;
    if (i < 49152) {   // Wf^T [64 n][768 k] = (Wcat2 @ out_w)^T, fp32 accumulate
      int n = (int)(i & 63), k = (int)(i >> 6);
      float acc = 0.f;
      if (k < 512) {
        const float* fr = P.fcw1 + (size_t)k * 512;
#pragma unroll 8
        for (int j = 0; j < 512; ++j) acc += fr[j] * P.outw[j * 64 + n];
        acc *= alpha;
      } else {
        const float* ir = P.injw1 + (size_t)(k - 512) * 512;
#pragma unroll 8
        for (int j = 0; j < 512; ++j) acc += ir[j] * P.outw[j * 64 + n];
      }
      P.wft[n * 768 + k] = f2b(acc);
      continue;
    }
    i -= 49152;
    if (i < 64) {      // bf = bias2 @ out_w + out_b (bias2 = alpha*fcb1+injb1)
      float acc = P.outb[i];
#pragma unroll 8
      for (int j = 0; j < 512; ++j)
        acc += (alpha * P.fcb1[j] + P.injb1[j]) * P.outw[j * 64 + i];
      P.bf[i] = acc;
      continue;
    }
    i -= 64;
    if (i < 512) { P.bias1[i] = alpha * P.fcb0[i] + P.injb0[i]; continue; }
  }
}

// ----------------------------------------------------------- CSR build ------
// Fixed-capacity CSR (row r occupies [r*CAP, r*CAP+cnt[r])) -> NO global
// exclusive scan, row_scan dispatch deleted. Per-bin scan across chunks:
// one wave per block spread over 158 CUs; packed u32 reads; u16 chunkoff.
__global__ __launch_bounds__(64) void col_scan(const unsigned* __restrict__ histRC,
                                               u16* __restrict__ chunkoff,
                                               int* __restrict__ cnt,
                                               float* __restrict__ deg_inv) {
  int r = blockIdx.x * 64 + threadIdx.x;
  if (r >= MPAD) return;
  if (r >= NBIN) { deg_inv[r] = 1.0f; return; }
  unsigned run = 0;
#pragma unroll 8
  for (int ch = 0; ch < NCH; ++ch) {
    chunkoff[(size_t)ch * NBIN + r] = (u16)(run & 0xffffu);
    run += histRC[(size_t)ch * NBIN + r];
  }
  int cr = (int)(run & 0xffffu);
  int dg = (int)(run >> 16);
  cnt[r] = cr;
  deg_inv[r] = 1.0f / (float)(dg > 1 ? dg : 1);
}

// placement: LDS cursor seeded from chunkoff (global state untouched ->
// replay-safe). rank guard prevents OOB if CAP were ever violated.
__global__ __launch_bounds__(256) void place_edges(const int* __restrict__ ei,
                                                   const u16* __restrict__ chunkoff,
                                                   int* __restrict__ csr) {
  __shared__ int cur[NBIN];   // 40 KB
  const int ch = blockIdx.x, t = threadIdx.x;
  const u16* co = chunkoff + (size_t)ch * NBIN;
  for (int i = t; i < NBIN; i += 256) cur[i] = co[i];
  __syncthreads();
  const int e0 = ch * CHUNK;
#pragma unroll
  for (int j = 0; j < CHUNK; j += 256) {
    int e = e0 + j + t;
    if (e < N_EDGES) {
      int r = ei[e];
      int c = ei[N_EDGES + e];
      int rank = atomicAdd(&cur[r], 1);   // LDS only; disjoint slots across chunks
      if (rank < CAP) csr[r * CAP + rank] = c;
    }
  }
}

// ---------------------------------------------------------------- GEMM ------
// 64x64 tile, TWO waves per block (128 threads): each wave computes 32x64
// (2x4 MFMA 16x16x32 frags). Proven R7/R9 config (~8 blocks/CU resident).
template<int K, bool RELU, bool SCALE, bool F32OUT>
__global__ __launch_bounds__(128) void gemm64(
    const u16* __restrict__ A, int lda,
    const u16* __restrict__ Bt,
    const float* __restrict__ bias,
    const float* __restrict__ scale,
    u16* __restrict__ Cb, float* __restrict__ Cf, int ldc)
{
  __shared__ u16 As[64 * 72];
  __shared__ u16 Bs[64 * 72];
  const int tid = threadIdx.x;
  const int m0 = blockIdx.x * 64;
  const int n0 = blockIdx.y * 64;
  const int wave = tid >> 6;
  const int lane = tid & 63;
  const int wr = wave * 32;
  const int lm = lane & 15;
  const int koff = (lane >> 4) * 8;

  const int srow = tid >> 2;          // stages rows srow and srow+32
  const int scol = (tid & 3) * 16;    // 16 u16 per row = 2 int4
  const u16* Ag0 = A + (size_t)(m0 + srow) * lda + scol;
  const u16* Ag1 = A + (size_t)(m0 + srow + 32) * lda + scol;
  const u16* Bg0 = Bt + (size_t)(n0 + srow) * K + scol;
  const u16* Bg1 = Bt + (size_t)(n0 + srow + 32) * K + scol;
  u16* Asw0 = &As[srow * 72 + scol];
  u16* Asw1 = &As[(srow + 32) * 72 + scol];
  u16* Bsw0 = &Bs[srow * 72 + scol];
  u16* Bsw1 = &Bs[(srow + 32) * 72 + scol];

  f32x4 acc[2][4] = {};

  int4 pa0 = *(const int4*)(Ag0),     pa1 = *(const int4*)(Ag0 + 8);
  int4 pa2 = *(const int4*)(Ag1),     pa3 = *(const int4*)(Ag1 + 8);
  int4 pb0 = *(const int4*)(Bg0),     pb1 = *(const int4*)(Bg0 + 8);
  int4 pb2 = *(const int4*)(Bg1),     pb3 = *(const int4*)(Bg1 + 8);

#pragma unroll
  for (int kb = 0; kb < K; kb += 64) {
    __syncthreads();
    *(int4*)Asw0 = pa0; *(int4*)(Asw0 + 8) = pa1;
    *(int4*)Asw1 = pa2; *(int4*)(Asw1 + 8) = pa3;
    *(int4*)Bsw0 = pb0; *(int4*)(Bsw0 + 8) = pb1;
    *(int4*)Bsw1 = pb2; *(int4*)(Bsw1 + 8) = pb3;
    __syncthreads();
    if (kb + 64 < K) {
      pa0 = *(const int4*)(Ag0 + kb + 64); pa1 = *(const int4*)(Ag0 + kb + 72);
      pa2 = *(const int4*)(Ag1 + kb + 64); pa3 = *(const int4*)(Ag1 + kb + 72);
      pb0 = *(const int4*)(Bg0 + kb + 64); pb1 = *(const int4*)(Bg0 + kb + 72);
      pb2 = *(const int4*)(Bg1 + kb + 64); pb3 = *(const int4*)(Bg1 + kb + 72);
    }
#pragma unroll
    for (int ks = 0; ks < 2; ++ks) {
      bf16x8 af[2], bf[4];
#pragma unroll
      for (int mi = 0; mi < 2; ++mi)
        af[mi] = *(const bf16x8*)&As[(wr + mi * 16 + lm) * 72 + ks * 32 + koff];
#pragma unroll
      for (int ni = 0; ni < 4; ++ni)
        bf[ni] = *(const bf16x8*)&Bs[(ni * 16 + lm) * 72 + ks * 32 + koff];
#pragma unroll
      for (int mi = 0; mi < 2; ++mi)
#pragma unroll
        for (int ni = 0; ni < 4; ++ni)
          acc[mi][ni] = __builtin_amdgcn_mfma_f32_16x16x32_bf16(af[mi], bf[ni], acc[mi][ni], 0, 0, 0);
    }
  }

  const int q4 = (lane >> 4) * 4;
#pragma unroll
  for (int mi = 0; mi < 2; ++mi) {
#pragma unroll
    for (int ni = 0; ni < 4; ++ni) {
      const int gc = n0 + ni * 16 + lm;
      const float bv = bias[gc];
#pragma unroll
      for (int r = 0; r < 4; ++r) {
        const int gr = m0 + wr + mi * 16 + q4 + r;
        float v = acc[mi][ni][r] + bv;
        if (RELU) v = fmaxf(v, 0.f);
        if (SCALE) v *= scale[gr];
        if (F32OUT) {
          if (gr < N_NODES) Cf[(size_t)gr * ldc + gc] = v;
        } else {
          Cb[(size_t)gr * ldc + gc] = f2b(v);
        }
      }
    }
  }
}

// ----------------------------------------------------------- aggregate ------
// One WAVE per node; paired gather: half-wave per neighbor, uint4/lane,
// unroll 4 -> 8 neighbors in flight; cross-half __shfl reduce. Fixed-CAP CSR:
// row r = csr[r*CAP .. r*CAP+cnt[r]).
__global__ __launch_bounds__(256) void aggregate(
    const u16* __restrict__ tmp, const int* __restrict__ cnt,
    const int* __restrict__ csr, u16* __restrict__ out0,
    u16* __restrict__ A1, u16* __restrict__ A2, int mode)
{
  const int wv = threadIdx.x >> 6;
  const int lane = threadIdx.x & 63;
  const int r = blockIdx.x * 4 + wv;          // grid = 2500 -> r in [0,10000)
  const int half = lane >> 5;
  const int q = lane & 31;
  const int beg = r * CAP, end = beg + cnt[r];
  const size_t feat = (size_t)q * 16;
  const char* tb = (const char*)tmp;

  float s0 = 0.f, s1 = 0.f, s2 = 0.f, s3 = 0.f, s4 = 0.f, s5 = 0.f, s6 = 0.f, s7 = 0.f;
  int i = beg;
  for (; i + 8 <= end; i += 8) {
    uint4 v[4];
#pragma unroll
    for (int j = 0; j < 4; ++j)
      v[j] = *(const uint4*)(tb + (size_t)csr[i + 2 * j + half] * 512 + feat);
#pragma unroll
    for (int j = 0; j < 4; ++j) {
      s0 += blo(v[j].x); s1 += bhi(v[j].x); s2 += blo(v[j].y); s3 += bhi(v[j].y);
      s4 += blo(v[j].z); s5 += bhi(v[j].z); s6 += blo(v[j].w); s7 += bhi(v[j].w);
    }
  }
  for (; i < end; i += 2) {
    int id = i + half;
    if (id < end) {
      uint4 v = *(const uint4*)(tb + (size_t)csr[id] * 512 + feat);
      s0 += blo(v.x); s1 += bhi(v.x); s2 += blo(v.y); s3 += bhi(v.y);
      s4 += blo(v.z); s5 += bhi(v.z); s6 += blo(v.w); s7 += bhi(v.w);
    }
  }
  const int src = lane ^ 32;
  s0 += __shfl(s0, src, 64); s1 += __shfl(s1, src, 64);
  s2 += __shfl(s2, src, 64); s3 += __shfl(s3, src, 64);
  s4 += __shfl(s4, src, 64); s5 += __shfl(s5, src, 64);
  s6 += __shfl(s6, src, 64); s7 += __shfl(s7, src, 64);

  if (half == 0) {
    uint4 pv;
    pv.x = pack2(s0, s1); pv.y = pack2(s2, s3);
    pv.z = pack2(s4, s5); pv.w = pack2(s6, s7);
    if (mode == 0) {
      *(uint4*)((char*)out0 + (size_t)r * 512 + feat) = pv;
    } else {
      uint4 pr;
      pr.x = pack2(fmaxf(s0, 0.f), fmaxf(s1, 0.f));
      pr.y = pack2(fmaxf(s2, 0.f), fmaxf(s3, 0.f));
      pr.z = pack2(fmaxf(s4, 0.f), fmaxf(s5, 0.f));
      pr.w = pack2(fmaxf(s6, 0.f), fmaxf(s7, 0.f));
      *(uint4*)((char*)A1 + (size_t)r * 1024 + feat) = pr;          // relu(h3)
      *(uint4*)((char*)A1 + (size_t)r * 1024 + 512 + feat) = pv;    // h3
      *(uint4*)((char*)A2 + (size_t)r * 1536 + 1024 + feat) = pv;   // h3 tail
    }
  }
}

// -------------------------------------------------------------- launch ------
extern "C" void kernel_launch(void* const* d_in, const int* in_sizes, int n_in,
                              void* d_out, int out_size, void* d_ws, size_t ws_size,
                              hipStream_t stream) {
  const int* ei = (const int*)d_in[1];   // int inputs arrive as int32

  char* p = (char*)d_ws;
  auto carve = [&](size_t bytes) -> void* {
    void* r = (void*)p;
    p += (bytes + 255) & ~(size_t)255;
    return r;
  };
  unsigned* histRC  = (unsigned*)carve((size_t)NCH * NBIN * 4);
  u16*    chunkoff  = (u16*)carve((size_t)NCH * NBIN * 2);
  int*    cnt       = (int*)carve(NBIN * 4);
  int*    csr       = (int*)carve((size_t)NBIN * CAP * 4);
  float*  deg_inv   = (float*)carve(MPAD * 4);
  float*  bias1     = (float*)carve(512 * 4);
  float*  bf        = (float*)carve(64 * 4);
  u16* xb   = (u16*)carve((size_t)MPAD * 256 * 2);
  u16* w0t  = (u16*)carve(65536 * 2);
  u16* w1t  = (u16*)carve(65536 * 2);
  u16* w2t  = (u16*)carve(65536 * 2);
  u16* wc1t = (u16*)carve(262144 * 2);
  u16* wft  = (u16*)carve(49152 * 2);
  u16* tmp  = (u16*)carve((size_t)MPAD * 256 * 2);
  u16* h    = (u16*)carve((size_t)MPAD * 256 * 2);
  u16* cat1 = (u16*)carve((size_t)MPAD * 512 * 2);
  u16* cat2 = (u16*)carve((size_t)MPAD * 768 * 2);

  PP pp;
  pp.x = (const float*)d_in[0];
  pp.ei = ei;
  pp.w0 = (const float*)d_in[2];
  pp.w1 = (const float*)d_in[4];
  pp.w2 = (const float*)d_in[6];
  pp.fcw0 = (const float*)d_in[8];
  pp.fcw1 = (const float*)d_in[10];
  pp.injw0 = (const float*)d_in[12];
  pp.injw1 = (const float*)d_in[14];
  pp.outw = (const float*)d_in[17];
  pp.fcb0 = (const float*)d_in[9];
  pp.injb0 = (const float*)d_in[13];
  pp.fcb1 = (const float*)d_in[11];
  pp.injb1 = (const float*)d_in[15];
  pp.alpha = (const float*)d_in[16];
  pp.outb = (const float*)d_in[18];
  pp.xb = xb; pp.w0t = w0t; pp.w1t = w1t; pp.w2t = w2t;
  pp.wc1t = wc1t; pp.wft = wft;
  pp.bias1 = bias1; pp.bf = bf;
  pp.histRC = histRC;

  const float* mp_b0 = (const float*)d_in[3];
  const float* mp_b1 = (const float*)d_in[5];
  const float* mp_b2 = (const float*)d_in[7];
  float* out = (float*)d_out;

  prep_hist<<<NCH + PREP_BLOCKS, 256, 0, stream>>>(pp);
  col_scan<<<MPAD / 64, 64, 0, stream>>>(histRC, chunkoff, cnt, deg_inv);
  place_edges<<<NCH, 256, 0, stream>>>(ei, chunkoff, csr);

  dim3 gmp(MPAD / 64, 4), gfc(MPAD / 64, 8), go(MPAD / 64, 1);
  // MP layer 1..3: tmp = relu(h @ W + b) * deg_inv ; h' = CSR-aggregate(tmp)
  gemm64<256, true, true, false><<<gmp, 128, 0, stream>>>(xb, 256, w0t, mp_b0, deg_inv, tmp, nullptr, 256);
  aggregate<<<2500, 256, 0, stream>>>(tmp, cnt, csr, h, nullptr, nullptr, 0);
  gemm64<256, true, true, false><<<gmp, 128, 0, stream>>>(h, 256, w1t, mp_b1, deg_inv, tmp, nullptr, 256);
  aggregate<<<2500, 256, 0, stream>>>(tmp, cnt, csr, h, nullptr, nullptr, 0);
  gemm64<256, true, true, false><<<gmp, 128, 0, stream>>>(h, 256, w2t, mp_b2, deg_inv, tmp, nullptr, 256);
  aggregate<<<2500, 256, 0, stream>>>(tmp, cnt, csr, nullptr, cat1, cat2, 1);
  // FC1 (+inj0 fused, K=512) -> relu -> cat2[:, 0:512]
  gemm64<512, true, false, false><<<gfc, 128, 0, stream>>>(cat1, 512, wc1t, bias1, nullptr, cat2, nullptr, 768);
  // FOLDED: out = cat2 @ (Wcat2 @ out_w) + (bias2 @ out_w + out_b), fp32 store
  gemm64<768, false, false, true><<<go, 128, 0, stream>>>(cat2, 768, wft, bf, nullptr, nullptr, out, 64);
}